// Round 2
// 3764.730 us; speedup vs baseline: 1.4615x; 1.4615x over previous
//
#include <hip/hip_runtime.h>
#include <hip/hip_bf16.h>

typedef short bf16x8_t __attribute__((ext_vector_type(8)));
typedef float f32x4_t __attribute__((ext_vector_type(4)));

#define LDSP(p) ((__attribute__((address_space(3))) void*)(p))
#define GLBP(p) ((const __attribute__((address_space(1))) void*)(p))

__device__ __forceinline__ unsigned short f2bf(float f){
  unsigned int x = __float_as_uint(f);
  x = (x + 0x7FFFu + ((x >> 16) & 1u)) >> 16;
  return (unsigned short)x;
}

// ---- device-coherent (cross-XCD) access helpers: bypass L1+L2, hit L3 coherence point ----
// NOTE: operands must be scalar or ext_vector types — HIP float4 is a struct and
// cannot bind to a "v" asm constraint ("indirect register inputs" error).
__device__ __forceinline__ void st_f4_agent(float* p, f32x4_t v){
  asm volatile("global_store_dwordx4 %0, %1, off sc0 sc1" :: "v"(p), "v"(v) : "memory");
}
__device__ __forceinline__ f32x4_t ld_f4_agent(const float* p){
  f32x4_t r;
  // waitcnt INSIDE the asm so the result is ready at asm exit (no hoisting hazard, rule #18)
  asm volatile("global_load_dwordx4 %0, %1, off sc0 sc1\n\ts_waitcnt vmcnt(0)"
               : "=&v"(r) : "v"(p) : "memory");
  return r;
}

// ---------------- fp32 -> bf16, 8 elements/thread ----------------
__global__ __launch_bounds__(256) void cvt_bf16(const float* __restrict__ in,
                                                unsigned short* __restrict__ out, int n8){
  int i = blockIdx.x * 256 + threadIdx.x;
  if (i >= n8) return;
  const float4* ip = (const float4*)in;
  float4 a = ip[2*i+0];
  float4 b = ip[2*i+1];
  uint4 u;
  u.x = (unsigned)f2bf(a.x) | ((unsigned)f2bf(a.y) << 16);
  u.y = (unsigned)f2bf(a.z) | ((unsigned)f2bf(a.w) << 16);
  u.z = (unsigned)f2bf(b.x) | ((unsigned)f2bf(b.y) << 16);
  u.w = (unsigned)f2bf(b.z) | ((unsigned)f2bf(b.w) << 16);
  ((uint4*)out)[i] = u;
}

// ---------------- gate = silu(x @ Wg^T + b_gate), bf16 MFMA (m97 structure) ----------------
__global__ __launch_bounds__(256) void gemm_gate(const unsigned short* __restrict__ A,
                                                 const unsigned short* __restrict__ B,
                                                 const float* __restrict__ bgate,
                                                 float* __restrict__ C){
  const int K = 4096, N = 4096;
  __shared__ __align__(16) unsigned short As[128*32];
  __shared__ __align__(16) unsigned short Bs[128*32];
  int tid = threadIdx.x;
  int lane = tid & 63, wave = tid >> 6;
  int wm = wave & 1, wn = wave >> 1;
  long m0 = (long)blockIdx.x * 128, n0 = (long)blockIdx.y * 128;
  f32x4_t acc[4][4];
  #pragma unroll
  for (int i=0;i<4;i++)
    #pragma unroll
    for (int j=0;j<4;j++) acc[i][j] = (f32x4_t){0.f,0.f,0.f,0.f};
  int fr = lane & 15, kg = lane >> 4;
  const unsigned short* Ab = A + m0 * K;
  const unsigned short* Bb = B + n0 * K;
  int row0 = tid >> 2, c8 = (tid & 3) * 8;
  for (int k0 = 0; k0 < K; k0 += 32){
    #pragma unroll
    for (int q = 0; q < 2; q++){
      int idx = q*256 + tid;
      int row = row0 + q*64;
      __builtin_amdgcn_global_load_lds(GLBP(Ab + (long)row*K + k0 + c8), LDSP(&As[idx*8]), 16, 0, 0);
      __builtin_amdgcn_global_load_lds(GLBP(Bb + (long)row*K + k0 + c8), LDSP(&Bs[idx*8]), 16, 0, 0);
    }
    __syncthreads();
    bf16x8_t af[4], bfv[4];
    #pragma unroll
    for (int i=0;i<4;i++){
      af[i]  = *(const bf16x8_t*)&As[(wm*64 + i*16 + fr)*32 + kg*8];
      bfv[i] = *(const bf16x8_t*)&Bs[(wn*64 + i*16 + fr)*32 + kg*8];
    }
    #pragma unroll
    for (int i=0;i<4;i++)
      #pragma unroll
      for (int j=0;j<4;j++)
        acc[i][j] = __builtin_amdgcn_mfma_f32_16x16x32_bf16(af[i], bfv[j], acc[i][j], 0, 0, 0);
    __syncthreads();
  }
  int crow = (lane >> 4) * 4, ccol = lane & 15;
  #pragma unroll
  for (int j=0;j<4;j++){
    long col = n0 + wn*64 + j*16 + ccol;
    float bgv = bgate[col];
    #pragma unroll
    for (int i=0;i<4;i++){
      #pragma unroll
      for (int r=0;r<4;r++){
        long rw = m0 + wm*64 + i*16 + crow + r;
        float v = acc[i][j][r] + bgv;
        float sv = v / (1.f + __expf(-v));
        __builtin_nontemporal_store(sv, &C[rw * N + col]);
      }
    }
  }
}

// ---------------- Mx stage 1: Zx[bk][i][s] = sum_j B1x[bk][i][j] * x[s][bk*64+j] ----------------
__global__ __launch_bounds__(256) void mx_s1(const float* __restrict__ B1x,
                                             const float* __restrict__ x,
                                             float* __restrict__ Zx){
  int bk = blockIdx.x;
  long s0 = (long)blockIdx.y * 64;
  int tid = threadIdx.x, lane = tid & 63, wv = tid >> 6;
  __shared__ __align__(16) float xs[64*68];
  __shared__ __align__(16) float zs[64*68];
  #pragma unroll
  for (int r=0;r<16;r++){
    int idx = r*256 + tid;
    int s = idx >> 6, j = idx & 63;
    xs[s*68 + j] = x[(s0 + s)*4096 + bk*64 + j];
  }
  float4 w[16];
  const float4* wp = (const float4*)(B1x + (long)bk*4096 + lane*64);
  #pragma unroll
  for (int jj=0;jj<16;jj++) w[jj] = wp[jj];
  __syncthreads();
  float acc[16];
  #pragma unroll
  for (int s=0;s<16;s++) acc[s] = 0.f;
  int sg = wv * 16;
  #pragma unroll
  for (int j4=0;j4<16;j4++){
    float4 wv4 = w[j4];
    #pragma unroll
    for (int s=0;s<16;s++){
      float4 xv = *(const float4*)&xs[(sg+s)*68 + j4*4];
      acc[s] += wv4.x*xv.x + wv4.y*xv.y + wv4.z*xv.z + wv4.w*xv.w;
    }
  }
  #pragma unroll
  for (int s=0;s<16;s++) zs[lane*68 + sg + s] = acc[s];
  __syncthreads();
  #pragma unroll
  for (int r=0;r<4;r++){
    int idx = r*256 + tid;
    int i = idx >> 4, sq = idx & 15;
    float4 v = *(const float4*)&zs[i*68 + sq*4];
    *(float4*)&Zx[(long)bk*524288 + (long)i*8192 + s0 + sq*4] = v;
  }
}

// ---------------- Mx stage 2: Mx[s][k*64+i] = sum_j B2x[k][i][j] * Zx[j][k][s] ----------------
__global__ __launch_bounds__(256) void mx_s2(const float* __restrict__ B2x,
                                             const float* __restrict__ Zx,
                                             float* __restrict__ Mx){
  int k = blockIdx.x;
  long s0 = (long)blockIdx.y * 64;
  int tid = threadIdx.x, lane = tid & 63, wv = tid >> 6;
  __shared__ __align__(16) float zt[64*68];
  __shared__ __align__(16) float ot[64*68];
  #pragma unroll
  for (int r=0;r<16;r++){
    int idx = r*256 + tid;
    int j = idx >> 6, s = idx & 63;
    zt[s*68 + j] = Zx[(long)j*524288 + (long)k*8192 + s0 + s];
  }
  float4 w[16];
  const float4* wp = (const float4*)(B2x + (long)k*4096 + lane*64);
  #pragma unroll
  for (int jj=0;jj<16;jj++) w[jj] = wp[jj];
  __syncthreads();
  float acc[16];
  #pragma unroll
  for (int s=0;s<16;s++) acc[s] = 0.f;
  int sg = wv * 16;
  #pragma unroll
  for (int j4=0;j4<16;j4++){
    float4 wv4 = w[j4];
    #pragma unroll
    for (int s=0;s<16;s++){
      float4 zv = *(const float4*)&zt[(sg+s)*68 + j4*4];
      acc[s] += wv4.x*zv.x + wv4.y*zv.y + wv4.z*zv.z + wv4.w*zv.w;
    }
  }
  #pragma unroll
  for (int s=0;s<16;s++) ot[(sg+s)*68 + lane] = acc[s];
  __syncthreads();
  #pragma unroll
  for (int r=0;r<4;r++){
    int idx = r*256 + tid;
    int s = idx >> 4, iq = idx & 15;
    float4 v = *(const float4*)&ot[s*68 + iq*4];
    *(float4*)&Mx[(s0 + s)*4096 + (long)k*64 + iq*4] = v;
  }
}

// ---------------- persistent recurrence: 64 WGs, one Monarch block each ----------------
// Sync redesign: NO acquire/release fences (they lower to whole-L2 buffer_inv/buffer_wbl2
// on gfx950). Z exchange + flags go point-to-point through the die-level L3 via sc0|sc1
// (L1+L2 bypass). Ordering: explicit s_waitcnt vmcnt(0) between Z stores and flag store.
// Flags padded to flags[blk*512 + t] so the 64 per-step flag writes hit 64 distinct lines.
__global__ __launch_bounds__(256) void rec_kernel(const float* __restrict__ B1h,
    const float* __restrict__ B2h, const float* __restrict__ h0,
    const float* __restrict__ Mx, const float* __restrict__ gate,
    const float* __restrict__ bias, float* __restrict__ Zrec,
    int* __restrict__ flags, float* __restrict__ outp, float* __restrict__ hout){
  int blk = blockIdx.x;
  int tid = threadIdx.x, lane = tid & 63, wv = tid >> 6;
  __shared__ __align__(16) float hs[16*68];  // hs[b][i]  (own 64-dim slice)
  __shared__ __align__(16) float zc[16*68];  // zc[b][j]  (gathered z column)
  float4 w1[16], w2[16];  // lane=i: B1h[blk][i][:], B2h[blk][i][:]
  {
    const float4* p1 = (const float4*)(B1h + (long)blk*4096 + lane*64);
    const float4* p2 = (const float4*)(B2h + (long)blk*4096 + lane*64);
    #pragma unroll
    for (int jj=0;jj<16;jj++){ w1[jj] = p1[jj]; w2[jj] = p2[jj]; }
  }
  float biasv = bias[blk*64 + lane];
  #pragma unroll
  for (int x=0;x<4;x++){
    int b = 4*wv + x;
    float hv = h0[(long)b*4096 + blk*64 + lane];
    hs[b*68 + lane] = hv;
    __builtin_nontemporal_store(hv, &hout[(long)b*4096 + blk*64 + lane]);  // h[0] = h0
  }
  __syncthreads();
  #pragma unroll 1
  for (int t = 0; t < 512; t++){
    float* Zp = Zrec + (long)(t & 1) * 65536;       // Z[parity][j][i][b]
    long base = (long)t*65536 + blk*64 + lane;
    float mxv[4], gv[4];
    #pragma unroll
    for (int x=0;x<4;x++){
      long a = base + (long)(4*wv + x)*4096;
      mxv[x] = __builtin_nontemporal_load(&Mx[a]);
      gv[x]  = __builtin_nontemporal_load(&gate[a]);
    }
    // stage 1: z[blk][i][b] = sum_j B1h[blk][i][j] * h[b][j]   (lane=i, wave -> 4 b's)
    float acc[4] = {0.f, 0.f, 0.f, 0.f};
    #pragma unroll
    for (int j4=0;j4<16;j4++){
      float4 wv4 = w1[j4];
      #pragma unroll
      for (int x=0;x<4;x++){
        float4 hv4 = *(const float4*)&hs[(4*wv+x)*68 + j4*4];
        acc[x] += wv4.x*hv4.x + wv4.y*hv4.y + wv4.z*hv4.z + wv4.w*hv4.w;
      }
    }
    f32x4_t zst = {acc[0], acc[1], acc[2], acc[3]};
    st_f4_agent(&Zp[blk*1024 + lane*16 + 4*wv], zst);
    // own Z stores (and everything else outstanding) acknowledged at coherence point
    asm volatile("s_waitcnt vmcnt(0)" ::: "memory");
    __syncthreads();                                // all 4 waves' Z stores are done
    if (tid == 0)
      __hip_atomic_store(&flags[blk*512 + t], 1, __ATOMIC_RELAXED, __HIP_MEMORY_SCOPE_AGENT);
    if (tid < 64){
      while (__hip_atomic_load(&flags[tid*512 + t], __ATOMIC_RELAXED, __HIP_MEMORY_SCOPE_AGENT) == 0){}
    }
    __syncthreads();
    // gather z column: zc[b][j] = Z[p][j][blk][b]  (fresh from L3, L1/L2 bypassed)
    {
      int j = tid >> 2, q = tid & 3;
      f32x4_t zv = ld_f4_agent(&Zp[j*1024 + blk*16 + q*4]);
      zc[(q*4+0)*68 + j] = zv[0];
      zc[(q*4+1)*68 + j] = zv[1];
      zc[(q*4+2)*68 + j] = zv[2];
      zc[(q*4+3)*68 + j] = zv[3];
    }
    __syncthreads();
    // stage 2 + pointwise epilogue
    float acc2[4] = {0.f, 0.f, 0.f, 0.f};
    #pragma unroll
    for (int j4=0;j4<16;j4++){
      float4 wv4 = w2[j4];
      #pragma unroll
      for (int x=0;x<4;x++){
        float4 zv4 = *(const float4*)&zc[(4*wv+x)*68 + j4*4];
        acc2[x] += wv4.x*zv4.x + wv4.y*zv4.y + wv4.z*zv4.z + wv4.w*zv4.w;
      }
    }
    #pragma unroll
    for (int x=0;x<4;x++){
      float pre = acc2[x] + mxv[x] + biasv;
      float hn = tanhf(pre);
      hs[(4*wv+x)*68 + lane] = hn;
      long a = base + (long)(4*wv + x)*4096;
      __builtin_nontemporal_store(hn, &hout[a + 65536]);      // h[t+1]
      __builtin_nontemporal_store(hn * gv[x], &outp[a]);      // output[t] = h_new * gate
    }
    __syncthreads();
  }
}

extern "C" void kernel_launch(void* const* d_in, const int* in_sizes, int n_in,
                              void* d_out, int out_size, void* d_ws, size_t ws_size,
                              hipStream_t stream){
  const float* x   = (const float*)d_in[0];
  const float* h0  = (const float*)d_in[1];
  const float* B1h = (const float*)d_in[2];
  const float* B2h = (const float*)d_in[3];
  const float* B1x = (const float*)d_in[4];
  const float* B2x = (const float*)d_in[5];
  const float* Wg  = (const float*)d_in[6];
  const float* bb  = (const float*)d_in[7];
  const float* bg  = (const float*)d_in[8];

  float* outp = (float*)d_out;                     // [512][16][4096]
  float* hout = outp + (size_t)33554432;           // [513][16][4096]

  char* w = (char*)d_ws;
  unsigned short* xb   = (unsigned short*)(w);                 // 64 MiB  bf16 x
  unsigned short* wbuf = (unsigned short*)(w + 67108864ULL);   // 32 MiB  bf16 Wg
  float* gate = (float*)(w + 100663296ULL);                    // 128 MiB
  float* Zx   = (float*)(w + 234881024ULL);                    // 128 MiB
  float* Mx   = (float*)(w + 369098752ULL);                    // 128 MiB
  float* Zrec = (float*)(w + 503316480ULL);                    // 512 KiB (ping-pong)
  int*   flags= (int*)(w + 503840768ULL);                      // 128 KiB

  (void)hipMemsetAsync(flags, 0, 512*64*sizeof(int), stream);
  cvt_bf16<<<16384, 256, 0, stream>>>(x, xb, 4194304);
  cvt_bf16<<<8192, 256, 0, stream>>>(Wg, wbuf, 2097152);
  gemm_gate<<<dim3(64, 32), 256, 0, stream>>>(xb, wbuf, bg, gate);
  mx_s1<<<dim3(64, 128), 256, 0, stream>>>(B1x, x, Zx);
  mx_s2<<<dim3(64, 128), 256, 0, stream>>>(B2x, Zx, Mx);
  rec_kernel<<<64, 256, 0, stream>>>(B1h, B2h, h0, Mx, gate, bb, Zrec, flags, outp, hout);
}